// Round 11
// baseline (178.732 us; speedup 1.0000x reference)
//
#include <hip/hip_runtime.h>
#include <hip/hip_bf16.h>
#include <cstdint>
#include <cmath>

#define SQL 2048
#define SKVL 2048
#define DD 128
#define NB 16
#define QBLK 64
#define KVB 32
#define NSTR 4
#define NT 16            // tiles per stream: 4 streams x 512 kv / KVB

typedef __attribute__((ext_vector_type(8))) short short8;
typedef __attribute__((ext_vector_type(4))) float f32x4;

__device__ __forceinline__ ushort f2bf(float x) {
    union { float f; uint32_t u; } v; v.f = x;
    uint32_t r = v.u + 0x7FFFu + ((v.u >> 16) & 1u);
    return (ushort)(r >> 16);
}

// fp32 -> bf16 with scale folded in; 8 elements/thread. (Used for Q.)
__global__ void convert_scale_k(const float* __restrict__ in, ushort* __restrict__ out, float scale) {
    size_t i = (size_t)blockIdx.x * blockDim.x + threadIdx.x;
    const f32x4* p = (const f32x4*)in + i * 2;
    f32x4 a = p[0], b = p[1];
    short8 o;
    o[0] = (short)f2bf(a[0] * scale);
    o[1] = (short)f2bf(a[1] * scale);
    o[2] = (short)f2bf(a[2] * scale);
    o[3] = (short)f2bf(a[3] * scale);
    o[4] = (short)f2bf(b[0] * scale);
    o[5] = (short)f2bf(b[1] * scale);
    o[6] = (short)f2bf(b[2] * scale);
    o[7] = (short)f2bf(b[3] * scale);
    *((short8*)out + i) = o;
}

// K fp32 [B][SKV][128] -> tiled swizzled bf16 [B][SKV/32][32 rows x 128 cols].
// Within an 8KB tile: elem (r,c) -> r*128 + ((c>>3)^(r&7))*8 + (c&7).
__global__ void convert_k_tiled(const float* __restrict__ in, ushort* __restrict__ out) {
    int gid = blockIdx.x * blockDim.x + threadIdx.x;   // one 16B out-chunk (8 elems)
    int c16 = gid & 15;
    int rg  = gid >> 4;            // b*SKV + kv
    int r   = rg & 31;
    int tile = rg >> 5;            // b*64 + kt
    const f32x4* p = (const f32x4*)(in + (size_t)rg * DD + c16 * 8);
    f32x4 a = p[0], b = p[1];
    short8 o;
    o[0] = (short)f2bf(a[0]); o[1] = (short)f2bf(a[1]);
    o[2] = (short)f2bf(a[2]); o[3] = (short)f2bf(a[3]);
    o[4] = (short)f2bf(b[0]); o[5] = (short)f2bf(b[1]);
    o[6] = (short)f2bf(b[2]); o[7] = (short)f2bf(b[3]);
    int cs = c16 ^ (r & 7);
    *(short8*)(out + ((size_t)tile << 12) + r * 128 + cs * 8) = o;
}

// V fp32 [B][SKV][128] -> V^T tiled bf16 [B][SKV/32][128 d-rows x 32 kv].
// kv permuted to the PV mfma slot map: logical chunk cs elem j -> kv =
// (j>>2)*16 + cs*4 + (j&3); storage chunk cs' = cs ^ ((d>>1)&3) (XOR swizzle).
__global__ void convert_vt_tiled(const float* __restrict__ v, ushort* __restrict__ vt) {
    __shared__ float tile[32][129];
    int bid = blockIdx.x;          // b*64 + kt
    int kt = bid & 63;
    int b  = bid >> 6;
    int tx = threadIdx.x;
    const float* src = v + ((size_t)b * SKVL + (size_t)kt * 32) * DD;
#pragma unroll
    for (int i = 0; i < 16; ++i) {
        int e = i * 256 + tx;      // 4096 elems
        tile[e >> 7][e & 127] = src[e];
    }
    __syncthreads();
    ushort* dst = vt + ((size_t)bid << 12);
#pragma unroll
    for (int i = 0; i < 2; ++i) {
        int q = i * 256 + tx;      // 512 chunks: d(128) x cs'(4)
        int d = q >> 2;
        int csp = q & 3;
        int cs = csp ^ ((d >> 1) & 3);
        short8 o;
#pragma unroll
        for (int j = 0; j < 8; ++j) {
            int kv = (j >> 2) * 16 + cs * 4 + (j & 3);
            o[j] = (short)f2bf(tile[kv][d]);
        }
        *(short8*)(dst + d * 32 + csp * 8) = o;
    }
}

#define GLD_LDS16(gsrc, ldst) \
    __builtin_amdgcn_global_load_lds((const __attribute__((address_space(1))) uint32_t*)(gsrc), \
                                     (__attribute__((address_space(3))) uint32_t*)(ldst), 16, 0, 0)

// Flash attention fwd. Grid = B*SQ/64 = 512 blocks, 512 thr (8 waves):
// wave (qg, s) = q-half (32 rows) x kv-stream (512 kv). Each wave owns TWO
// 16-q subtiles sharing every K/V LDS fragment read (1 ds_read -> 2 MFMAs),
// halving LDS-pipe traffic vs 16-row waves. 4 streams single-buffered in
// LDS (64KB -> 2 blocks/CU, 16 waves/CU). 4-way stream merge in LDS.
__global__ __launch_bounds__(512, 4) void fattn(
    const ushort* __restrict__ qb, const ushort* __restrict__ kbt,
    const ushort* __restrict__ vbt, float* __restrict__ out)
{
    __shared__ char smem[65536];
    short8* kls = (short8*)smem;            // [stream][512] 8KB tiles
    short8* vls = (short8*)(smem + 32768);  // [stream][512]

    int bid = blockIdx.x;
    // XCD-bijective swizzle: 512 = 8 XCDs x 64 -> 2 batches' K/V per XCD L2.
    int swz = (bid & 7) * 64 + (bid >> 3);
    int b  = swz >> 5;
    int qt = swz & 31;
    int lane = threadIdx.x & 63;
    int w = threadIdx.x >> 6;        // 0..7
    int s = w >> 1;                  // kv-stream 0..3
    int qg = w & 1;                  // q-half
    int g = lane >> 4;
    int qi = lane & 15;
    int rx = qi & 7;
    int vx = g ^ ((qi >> 1) & 3);    // V chunk swizzle, constant per lane

    const short8* kl = kls + s * 512;
    const short8* vl = vls + s * 512;
    // staging role: qg=0 stages this stream's K tile, qg=1 its V tile (8KB)
    const ushort* kb_s = kbt + ((size_t)(b * 64 + s * 16) << 12);
    const ushort* vb_s = vbt + ((size_t)(b * 64 + s * 16) << 12);
    const char* gsrc = qg ? (const char*)vb_s : (const char*)kb_s;
    char* ldst = qg ? (char*)(vls + s * 512) : (char*)(kls + s * 512);

#define STAGE(t) do { const char* _g = gsrc + ((size_t)(t) << 13); \
    _Pragma("unroll") for (int _i = 0; _i < 8; ++_i) \
        GLD_LDS16(_g + _i * 1024 + lane * 16, ldst + _i * 1024); } while (0)

    // Q fragments for both subtiles: lane holds q=qi, d-slots ks*32 + g*8 + j.
    const ushort* qptr = qb + ((size_t)b * SQL + qt * QBLK + qg * 32 + qi) * DD;
    short8 qf[2][4];
#pragma unroll
    for (int sub = 0; sub < 2; ++sub)
#pragma unroll
        for (int ks = 0; ks < 4; ++ks)
            qf[sub][ks] = *(const short8*)(qptr + sub * 16 * DD + ks * 32 + g * 8);

    f32x4 acc[2][8];
#pragma unroll
    for (int sub = 0; sub < 2; ++sub)
#pragma unroll
        for (int i = 0; i < 8; ++i) acc[sub][i] = (f32x4)0.f;
    float m[2] = {-1e30f, -1e30f}, lsum[2] = {0.f, 0.f};

    STAGE(0);
    __syncthreads();

    for (int t = 0; t < NT; ++t) {
        // ---- QK^T: each K fragment read once, feeds both q-subtiles ----
        f32x4 st0[2], st1[2];
        __builtin_amdgcn_s_setprio(1);
#pragma unroll
        for (int kvs = 0; kvs < 2; ++kvs) {
            f32x4 a0 = (f32x4)0.f, a1 = (f32x4)0.f;
            int r = kvs * 16 + qi;
#pragma unroll
            for (int ks = 0; ks < 4; ++ks) {
                short8 kf = kl[r * 16 + ((ks * 4 + g) ^ rx)];
                a0 = __builtin_amdgcn_mfma_f32_16x16x32_bf16(kf, qf[0][ks], a0, 0, 0, 0);
                a1 = __builtin_amdgcn_mfma_f32_16x16x32_bf16(kf, qf[1][ks], a1, 0, 0, 0);
            }
            st0[kvs] = a0; st1[kvs] = a1;
        }
        __builtin_amdgcn_s_setprio(0);
        // ---- online softmax (defer-max, shfls on cold path), both subtiles ----
        float vm0 = fmaxf(fmaxf(fmaxf(st0[0][0], st0[0][1]), fmaxf(st0[0][2], st0[0][3])),
                          fmaxf(fmaxf(st0[1][0], st0[1][1]), fmaxf(st0[1][2], st0[1][3])));
        float vm1 = fmaxf(fmaxf(fmaxf(st1[0][0], st1[0][1]), fmaxf(st1[0][2], st1[0][3])),
                          fmaxf(fmaxf(st1[1][0], st1[1][1]), fmaxf(st1[1][2], st1[1][3])));
        if (__any((vm0 > m[0] + 11.5f) || (vm1 > m[1] + 11.5f))) {
            float t0 = fmaxf(vm0, __shfl_xor(vm0, 16)); t0 = fmaxf(t0, __shfl_xor(t0, 32));
            float t1 = fmaxf(vm1, __shfl_xor(vm1, 16)); t1 = fmaxf(t1, __shfl_xor(t1, 32));
            float mn0 = fmaxf(m[0], t0), mn1 = fmaxf(m[1], t1);
            float a0 = exp2f(m[0] - mn0), a1 = exp2f(m[1] - mn1);
            m[0] = mn0; m[1] = mn1;
            lsum[0] *= a0; lsum[1] *= a1;
#pragma unroll
            for (int i = 0; i < 8; ++i) { acc[0][i] *= a0; acc[1][i] *= a1; }
        }
        union { short8 v; uint32_t u[4]; } P0, P1;
        {
            float pvv[8];
#pragma unroll
            for (int kvs = 0; kvs < 2; ++kvs) {
                pvv[kvs * 4 + 0] = exp2f(st0[kvs][0] - m[0]);
                pvv[kvs * 4 + 1] = exp2f(st0[kvs][1] - m[0]);
                pvv[kvs * 4 + 2] = exp2f(st0[kvs][2] - m[0]);
                pvv[kvs * 4 + 3] = exp2f(st0[kvs][3] - m[0]);
            }
            lsum[0] += ((pvv[0] + pvv[1]) + (pvv[2] + pvv[3])) + ((pvv[4] + pvv[5]) + (pvv[6] + pvv[7]));
#pragma unroll
            for (int i = 0; i < 4; ++i)
                asm("v_cvt_pk_bf16_f32 %0, %1, %2" : "=v"(P0.u[i]) : "v"(pvv[2 * i]), "v"(pvv[2 * i + 1]));
        }
        {
            float pvv[8];
#pragma unroll
            for (int kvs = 0; kvs < 2; ++kvs) {
                pvv[kvs * 4 + 0] = exp2f(st1[kvs][0] - m[1]);
                pvv[kvs * 4 + 1] = exp2f(st1[kvs][1] - m[1]);
                pvv[kvs * 4 + 2] = exp2f(st1[kvs][2] - m[1]);
                pvv[kvs * 4 + 3] = exp2f(st1[kvs][3] - m[1]);
            }
            lsum[1] += ((pvv[0] + pvv[1]) + (pvv[2] + pvv[3])) + ((pvv[4] + pvv[5]) + (pvv[6] + pvv[7]));
#pragma unroll
            for (int i = 0; i < 4; ++i)
                asm("v_cvt_pk_bf16_f32 %0, %1, %2" : "=v"(P1.u[i]) : "v"(pvv[2 * i]), "v"(pvv[2 * i + 1]));
        }
        // ---- PV: each V fragment read once, feeds both q-subtiles ----
        __builtin_amdgcn_s_setprio(1);
#pragma unroll
        for (int dt = 0; dt < 8; ++dt) {
            short8 vf = vl[(dt * 16 + qi) * 4 + vx];
            acc[0][dt] = __builtin_amdgcn_mfma_f32_16x16x32_bf16(vf, P0.v, acc[0][dt], 0, 0, 0);
            acc[1][dt] = __builtin_amdgcn_mfma_f32_16x16x32_bf16(vf, P1.v, acc[1][dt], 0, 0, 0);
        }
        __builtin_amdgcn_s_setprio(0);
        __syncthreads();                 // all waves done reading tile t
        if (t + 1 < NT) STAGE(t + 1);    // overwrite single buffer
        __syncthreads();                 // staged writes landed (vmcnt0 drain)
    }

    // ---- 4-way stream merge in LDS (two rounds, one per q-subtile) ----
    float* mb = (float*)smem;            // [qg][s-1][lane][36] = 55.3KB
#pragma unroll 2
    for (int sub = 0; sub < 2; ++sub) {
        __syncthreads();
        if (s > 0) {
            float* dst = mb + (((qg * 3) + (s - 1)) * 64 + lane) * 36;
#pragma unroll
            for (int dt = 0; dt < 8; ++dt)
                *(f32x4*)(dst + dt * 4) = acc[sub][dt];
            dst[32] = m[sub];
            dst[33] = lsum[sub];
        }
        __syncthreads();
        if (s == 0) {
#pragma unroll
            for (int ps = 0; ps < 3; ++ps) {
                const float* src = mb + (((qg * 3) + ps) * 64 + lane) * 36;
                float mp = src[32], lp = src[33];
                float mf = fmaxf(m[sub], mp);
                float fa = exp2f(m[sub] - mf), fp = exp2f(mp - mf);
                m[sub] = mf;
                lsum[sub] = lsum[sub] * fa + lp * fp;
#pragma unroll
                for (int dt = 0; dt < 8; ++dt) {
                    f32x4 ap = *(const f32x4*)(src + dt * 4);
                    acc[sub][dt] = acc[sub][dt] * fa + ap * fp;
                }
            }
        }
    }
    if (s == 0) {
#pragma unroll 2
        for (int sub = 0; sub < 2; ++sub) {
            float l = lsum[sub];
            l += __shfl_xor(l, 16);
            l += __shfl_xor(l, 32);
            float inv = 1.f / l;
            float* optr = out + ((size_t)b * SQL + qt * QBLK + qg * 32 + sub * 16 + qi) * DD + g * 4;
#pragma unroll
            for (int dt = 0; dt < 8; ++dt) {
                f32x4 o;
                o[0] = acc[sub][dt][0] * inv; o[1] = acc[sub][dt][1] * inv;
                o[2] = acc[sub][dt][2] * inv; o[3] = acc[sub][dt][3] * inv;
                *(f32x4*)(optr + dt * 16) = o;
            }
        }
    }
#undef STAGE
}

extern "C" void kernel_launch(void* const* d_in, const int* in_sizes, int n_in,
                              void* d_out, int out_size, void* d_ws, size_t ws_size,
                              hipStream_t stream) {
    const float* q = (const float*)d_in[0];
    const float* k = (const float*)d_in[1];
    const float* v = (const float*)d_in[2];
    float* out = (float*)d_out;

    uint8_t* w = (uint8_t*)d_ws;
    size_t tsz = (size_t)NB * SQL * DD * sizeof(ushort);  // 8 MB per tensor
    ushort* qb  = (ushort*)w;
    ushort* kbt = (ushort*)(w + tsz);
    ushort* vbt = (ushort*)(w + 2 * tsz);

    float qscale = 1.4426950408889634f / sqrtf((float)DD);
    int n8 = NB * SQL * DD / 8;
    convert_scale_k<<<n8 / 256, 256, 0, stream>>>(q, qb, qscale);
    convert_k_tiled<<<NB * SKVL * 16 / 256, 256, 0, stream>>>(k, kbt);
    convert_vt_tiled<<<NB * (SKVL / 32), 256, 0, stream>>>(v, vbt);
    fattn<<<NB * (SQL / QBLK), 512, 0, stream>>>(qb, kbt, vbt, out);
}